// Round 11
// baseline (522.970 us; speedup 1.0000x reference)
//
#include <hip/hip_runtime.h>

#define NNODES 100000
#define NEDGES 3200000
#define NGRAPH 1000
#define NPG    100
#define QTR    25          // nodes per k_fused block (quarter graph)
#define MDIM   32
#define NCDIM  10
#define NB     98          // ceil(NNODES/1024) scan blocks

#define NPART   8          // scatter partitions (== XCD count)
#define PSIZE   12500      // nodes per partition
#define FCHUNK  6250       // edges per chunk
#define FBLKS   (NEDGES / FCHUNK)   // 512 chunks

// ws layout (float units):
//  xd4   @ 0        : 100000 float4  (x0,x1,x2,dinv)      1.6 MB
//  a4    @ 400000   : 100000 float4  (a0,a1,a2,dinv)      1.6 MB
//  cnt   @ 800000   : 100000 int
//  rowptr@ 900000   : 100000 int
//  cursor@ 1000000  : 100000 int
//  bsum  @ 1099000  : 128 int   | boff @ 1099128 : 128 int
//  slot  @ 1100000  : 3200064 int (64-entry pad, memset 0)
//  pp    @ 4300100  : 4000*128 float (quarter-graph pool partials)
#define WS_FLOATS 4812100   // 19.25 MB total (27.2 MB proven available)

// ---------------- K1: in-degree histogram, XCD-partitioned ----------------
__global__ __launch_bounds__(256) void k_count(const int* __restrict__ col,
                                               int* __restrict__ cnt) {
    int part  = blockIdx.x & (NPART - 1);
    int chunk = blockIdx.x >> 3;
    int base  = chunk * FCHUNK;
    int end   = base + FCHUNK;
    int clo   = part * PSIZE;
    int chi   = clo + PSIZE;
    for (int e = base + threadIdx.x; e < end; e += 256) {
        int c = col[e];
        if (c >= clo && c < chi) atomicAdd(&cnt[c], 1);
    }
}

// ---------------- K2a: per-block sums of cnt ----------------
__global__ __launch_bounds__(1024) void k_bsum(const int* __restrict__ cnt,
                                               int* __restrict__ bsum) {
    __shared__ int wsum[16];
    int b = blockIdx.x, t = threadIdx.x;
    int i = b * 1024 + t;
    int v = (i < NNODES) ? cnt[i] : 0;
    for (int off = 32; off; off >>= 1) v += __shfl_down(v, off);
    if ((t & 63) == 0) wsum[t >> 6] = v;
    __syncthreads();
    if (t < 16) {
        int s = wsum[t];
        for (int off = 8; off; off >>= 1) s += __shfl_down(s, off);
        if (t == 0) bsum[b] = s;
    }
}

// ---------------- K2b: exclusive scan of NB block sums ----------------
__global__ void k_bscan(const int* __restrict__ bsum, int* __restrict__ boff) {
    __shared__ int s[128];
    int t = threadIdx.x;
    int v = (t < NB) ? bsum[t] : 0;
    s[t] = v;
    __syncthreads();
    for (int off = 1; off < 128; off <<= 1) {
        int u = (t >= off) ? s[t - off] : 0;
        __syncthreads();
        s[t] += u;
        __syncthreads();
    }
    if (t < NB) boff[t] = s[t] - v;   // exclusive
}

// ---------------- K2c: block-local scan + offsets; also xd4/cursor ----------------
__global__ __launch_bounds__(1024) void k_scan2(const int* __restrict__ cnt,
                                                const int* __restrict__ boff,
                                                const float* __restrict__ x,
                                                int* __restrict__ rowptr,
                                                int* __restrict__ cursor,
                                                float4* __restrict__ xd4) {
    __shared__ int s[1024];
    int b = blockIdx.x, t = threadIdx.x;
    int i = b * 1024 + t;
    int c = (i < NNODES) ? cnt[i] : 0;
    s[t] = c;
    __syncthreads();
    for (int off = 1; off < 1024; off <<= 1) {
        int u = (t >= off) ? s[t - off] : 0;
        __syncthreads();
        s[t] += u;
        __syncthreads();
    }
    if (i < NNODES) {
        int excl = s[t] - c + boff[b];
        rowptr[i] = excl;
        cursor[i] = excl;
        float di = rsqrtf((float)c + 1.0f);
        xd4[i] = make_float4(x[3 * i], x[3 * i + 1], x[3 * i + 2], di);
    }
}

// ---------------- K3: XCD-partitioned scatter into CSR slots ----------------
__global__ __launch_bounds__(256) void k_fill(const int* __restrict__ ei,
                                              int* __restrict__ cursor,
                                              int* __restrict__ slot) {
    int part  = blockIdx.x & (NPART - 1);
    int chunk = blockIdx.x >> 3;
    int base  = chunk * FCHUNK;
    int end   = base + FCHUNK;
    int clo   = part * PSIZE;
    int chi   = clo + PSIZE;
    for (int e = base + threadIdx.x; e < end; e += 256) {
        int c = ei[NEDGES + e];
        if (c >= clo && c < chi) {
            int r = ei[e];
            slot[atomicAdd(&cursor[c], 1)] = r;
        }
    }
}

// ---------------- K4: a4[i]; 8-deep unclamped gather pipeline ----------------
__global__ void k_a(const int* __restrict__ rowptr, const int* __restrict__ cnt,
                    const int* __restrict__ slot, const float4* __restrict__ xd4,
                    float4* __restrict__ a4) {
    int i = blockIdx.x * blockDim.x + threadIdx.x;
    if (i >= NNODES) return;
    int s = rowptr[i], d = cnt[i];
    float ax = 0.f, ay = 0.f, az = 0.f;
    for (int k = 0; k < d; k += 8) {
        float4 xr[8];
        #pragma unroll
        for (int j = 0; j < 8; ++j) xr[j] = xd4[slot[s + k + j]];  // pad-safe
        #pragma unroll
        for (int j = 0; j < 8; ++j) {
            float u = (k + j < d) ? xr[j].w : 0.f;
            ax += u * xr[j].x; ay += u * xr[j].y; az += u * xr[j].z;
        }
    }
    float4 xi = xd4[i];
    float di = xi.w;
    a4[i] = make_float4(di * (ax + di * xi.x),
                        di * (ay + di * xi.y),
                        di * (az + di * xi.z), di);
}

// ---------------- K5: quarter-graph blocks; 16-deep VMEM broadcast gather ---------
__global__ __launch_bounds__(256, 4) void k_fused(
    const int* __restrict__ rowptr, const int* __restrict__ cnt,
    const int* __restrict__ slot, const float4* __restrict__ a4,
    const float* __restrict__ W1, const float* __restrict__ b1,
    const float* __restrict__ W2, const float* __restrict__ b2,
    float* __restrict__ pp)
{
    __shared__ float aggh[28 * 65];    // 7.3 KB (rows 25..27 phantom pad)
    __shared__ float pools[4 * 128];

    int b = blockIdx.x;
    int g = b >> 2, q = b & 3;
    int t = threadIdx.x;
    int w = t >> 6;            // wave 0..3; owns nodes n = w + 4*i
    int lane = t & 63;         // phase 1: feature f; phase 2: output pair

    float w10 = W1[lane], w11 = W1[64 + lane], w12 = W1[128 + lane], b1f = b1[lane];
    int nn = (w == 0) ? 7 : 6;          // 25 = 7+6+6+6

    // ---- phase 1: gather+aggregate; VMEM broadcast loads, 16 in flight ----
    for (int i = 0; i < nn; ++i) {
        int n = w + 4 * i;
        int node = g * NPG + q * QTR + n;
        int s = rowptr[node], d = cnt[node];
        float acc = 0.f;
        for (int base = 0; base < d; base += 64) {
            int m = min(64, d - base);
            int sl = slot[s + base + lane];            // coalesced, pad-safe
            for (int k0 = 0; k0 < m; k0 += 16) {
                float4 pre[16];
                #pragma unroll
                for (int j = 0; j < 16; ++j) {
                    // ds_bpermute keeps the index in a VGPR -> per-lane VMEM
                    // broadcast load (in-order vmcnt, partial waits), not s_load
                    int r = __builtin_amdgcn_ds_bpermute((k0 + j) << 2, sl);
                    pre[j] = a4[r];
                }
                #pragma unroll
                for (int j = 0; j < 16; ++j) {
                    float4 ar = pre[j];
                    float wgt = (k0 + j < m) ? ar.w : 0.f;   // wave-uniform mask
                    float h = fmaxf(ar.x * w10 + ar.y * w11 + ar.z * w12 + b1f, 0.f);
                    acc += wgt * h;
                }
            }
        }
        float4 ai = a4[node];
        float hs = fmaxf(ai.x * w10 + ai.y * w11 + ai.z * w12 + b1f, 0.f);
        aggh[n * 65 + lane] = ai.w * (acc + ai.w * hs);
    }
    // no barrier: each wave reads back only rows it wrote (same-wave lgkmcnt)

    // ---- phase 2: [<=7][64] @ [64][128], acc in registers, W2 streamed from L2 ----
    float2 b2v = *(const float2*)&b2[2 * lane];
    float acc0[7], acc1[7];
    #pragma unroll
    for (int i = 0; i < 7; ++i) { acc0[i] = 0.f; acc1[i] = 0.f; }
    {
        float2 wv0 = *(const float2*)&W2[2 * lane];
        float2 wv1 = *(const float2*)&W2[128 + 2 * lane];
        for (int f = 0; f < 64; ++f) {
            float2 wnx = (f + 2 < 64) ? *(const float2*)&W2[(f + 2) * 128 + 2 * lane] : wv0;
            #pragma unroll
            for (int i = 0; i < 7; ++i) {
                float rv = aggh[(w + 4 * i) * 65 + f];   // junk rows discarded below
                acc0[i] += rv * wv0.x;
                acc1[i] += rv * wv0.y;
            }
            wv0 = wv1; wv1 = wnx;
        }
    }
    float pool0 = 0.f, pool1 = 0.f;
    #pragma unroll
    for (int i = 0; i < 7; ++i) {
        if (i < nn) {
            pool0 += fmaxf(acc0[i] + b2v.x, 0.f);
            pool1 += fmaxf(acc1[i] + b2v.y, 0.f);
        }
    }
    pools[w * 128 + 2 * lane]     = pool0;
    pools[w * 128 + 2 * lane + 1] = pool1;
    __syncthreads();
    if (t < 128)
        pp[b * 128 + t] = pools[t] + pools[128 + t] + pools[256 + t] + pools[384 + t];
}

// ---------------- K6: merge quarter-graph pools + MLP head ----------------
__global__ __launch_bounds__(128) void k_head(
    const float* __restrict__ pp, const float* __restrict__ mv,
    const float* __restrict__ Wc1, const float* __restrict__ bc1,
    const float* __restrict__ Wc2, const float* __restrict__ bc2,
    float* __restrict__ out)
{
    __shared__ float zbuf[160];
    __shared__ float zz[64];
    int g = blockIdx.x;
    int t = threadIdx.x;
    if (t < 128)
        zbuf[t] = (pp[(4 * g) * 128 + t] + pp[(4 * g + 1) * 128 + t] +
                   pp[(4 * g + 2) * 128 + t] + pp[(4 * g + 3) * 128 + t]) * (1.0f / NPG);
    if (t < MDIM) zbuf[128 + t] = mv[g * MDIM + t];
    __syncthreads();
    if (t < 64) {
        float v = bc1[t];
        for (int k = 0; k < 160; ++k) v += zbuf[k] * Wc1[k * 64 + t];
        zz[t] = fmaxf(v, 0.f);
    }
    __syncthreads();
    if (t < NCDIM) {
        float o = bc2[t];
        #pragma unroll
        for (int k = 0; k < 64; ++k) o += zz[k] * Wc2[k * NCDIM + t];
        out[g * NCDIM + t] = o;
    }
}

extern "C" void kernel_launch(void* const* d_in, const int* in_sizes, int n_in,
                              void* d_out, int out_size, void* d_ws, size_t ws_size,
                              hipStream_t stream) {
    const float* x   = (const float*)d_in[0];
    const int*   ei  = (const int*)d_in[1];   // int64 in ref -> int32 on device
    const float* mv  = (const float*)d_in[3];
    const float* W1  = (const float*)d_in[4];
    const float* b1  = (const float*)d_in[5];
    const float* W2  = (const float*)d_in[6];
    const float* b2  = (const float*)d_in[7];
    const float* Wc1 = (const float*)d_in[8];
    const float* bc1 = (const float*)d_in[9];
    const float* Wc2 = (const float*)d_in[10];
    const float* bc2 = (const float*)d_in[11];
    float* out = (float*)d_out;

    if (ws_size < (size_t)WS_FLOATS * sizeof(float)) return;  // clean fail, no fault

    float*  ws     = (float*)d_ws;
    float4* xd4    = (float4*)(ws);             // 100000 float4
    float4* a4     = (float4*)(ws + 400000);    // 100000 float4
    int*    cnt    = (int*)(ws + 800000);
    int*    rowptr = (int*)(ws + 900000);
    int*    cursor = (int*)(ws + 1000000);
    int*    bsum   = (int*)(ws + 1099000);      // 128 ints
    int*    boff   = (int*)(ws + 1099128);      // 128 ints
    int*    slot   = (int*)(ws + 1100000);      // 3200064 ints (padded)
    float*  pp     = (float*)(ws + 4300100);    // 4000*128 floats

    hipMemsetAsync(cnt, 0, (size_t)NNODES * sizeof(int), stream);
    hipMemsetAsync(slot + NEDGES, 0, 64 * sizeof(int), stream);  // pad -> node 0

    const int* col = ei + NEDGES;

    k_count<<<FBLKS * NPART, 256, 0, stream>>>(col, cnt);
    k_bsum <<<NB, 1024, 0, stream>>>(cnt, bsum);
    k_bscan<<<1, 128, 0, stream>>>(bsum, boff);
    k_scan2<<<NB, 1024, 0, stream>>>(cnt, boff, x, rowptr, cursor, xd4);
    k_fill <<<FBLKS * NPART, 256, 0, stream>>>(ei, cursor, slot);
    k_a    <<<(NNODES + 255) / 256, 256, 0, stream>>>(rowptr, cnt, slot, xd4, a4);
    k_fused<<<4 * NGRAPH, 256, 0, stream>>>(rowptr, cnt, slot, a4,
                                            W1, b1, W2, b2, pp);
    k_head <<<NGRAPH, 128, 0, stream>>>(pp, mv, Wc1, bc1, Wc2, bc2, out);
}

// Round 12
// 476.940 us; speedup vs baseline: 1.0965x; 1.0965x over previous
//
#include <hip/hip_runtime.h>

#define NNODES 100000
#define NEDGES 3200000
#define NGRAPH 1000
#define NPG    100
#define HALF   50
#define MDIM   32
#define NCDIM  10
#define NB     98          // ceil(NNODES/1024) scan blocks

#define NPART   8          // scatter partitions (== XCD count)
#define PSIZE   12500      // nodes per partition
#define FCHUNK  6250       // edges per chunk
#define FBLKS   (NEDGES / FCHUNK)   // 512 chunks

// ---- Path B layout (proven ws budget, 18.2 MB) ----
#define B_XD4    0
#define B_A4     400000
#define B_CNT    800000
#define B_ROWPTR 900000     // 100032 (rowptr[N] fits in pad)
#define B_CURSOR 1000032
#define B_BSUM   1100064
#define B_BOFF   1100192
#define B_SLOT   1100320    // 3200064
#define B_PP     4300384    // 2000*128
#define WS_B     (4300384 + 256000)            // 18.2 MB

// ---- Path A layout (40.4 MB, runtime-gated) ----
#define A_ROWPTR 0          // 100032
#define A_A4     100032     // 400000
#define A_SLOT   500032     // 3200064 (64 pad)
#define A_G1     3700096    // 6400000 f32  (build scratch aliased below)
#define A_CNT    3700096    // 100000 (dead before g1 written)
#define A_CURSOR 3800096
#define A_XD4    3900096    // 400000
#define A_BSUM   4300096
#define A_BOFF   4300224
#define WS_A     (3700096 + 6400000)           // 40.4 MB

// ---------------- K1: in-degree histogram, XCD-partitioned ----------------
__global__ __launch_bounds__(256) void k_count(const int* __restrict__ col,
                                               int* __restrict__ cnt) {
    int part  = blockIdx.x & (NPART - 1);
    int chunk = blockIdx.x >> 3;
    int base  = chunk * FCHUNK;
    int end   = base + FCHUNK;
    int clo   = part * PSIZE;
    int chi   = clo + PSIZE;
    for (int e = base + threadIdx.x; e < end; e += 256) {
        int c = col[e];
        if (c >= clo && c < chi) atomicAdd(&cnt[c], 1);
    }
}

// ---------------- K2a: per-block sums of cnt ----------------
__global__ __launch_bounds__(1024) void k_bsum(const int* __restrict__ cnt,
                                               int* __restrict__ bsum) {
    __shared__ int wsum[16];
    int b = blockIdx.x, t = threadIdx.x;
    int i = b * 1024 + t;
    int v = (i < NNODES) ? cnt[i] : 0;
    for (int off = 32; off; off >>= 1) v += __shfl_down(v, off);
    if ((t & 63) == 0) wsum[t >> 6] = v;
    __syncthreads();
    if (t < 16) {
        int s = wsum[t];
        for (int off = 8; off; off >>= 1) s += __shfl_down(s, off);
        if (t == 0) bsum[b] = s;
    }
}

// ---------------- K2b: exclusive scan of NB block sums ----------------
__global__ void k_bscan(const int* __restrict__ bsum, int* __restrict__ boff) {
    __shared__ int s[128];
    int t = threadIdx.x;
    int v = (t < NB) ? bsum[t] : 0;
    s[t] = v;
    __syncthreads();
    for (int off = 1; off < 128; off <<= 1) {
        int u = (t >= off) ? s[t - off] : 0;
        __syncthreads();
        s[t] += u;
        __syncthreads();
    }
    if (t < NB) boff[t] = s[t] - v;   // exclusive
}

// ---------------- K2c: block-local scan + offsets; also xd4/cursor ----------------
__global__ __launch_bounds__(1024) void k_scan2(const int* __restrict__ cnt,
                                                const int* __restrict__ boff,
                                                const float* __restrict__ x,
                                                int* __restrict__ rowptr,
                                                int* __restrict__ cursor,
                                                float4* __restrict__ xd4) {
    __shared__ int s[1024];
    int b = blockIdx.x, t = threadIdx.x;
    int i = b * 1024 + t;
    int c = (i < NNODES) ? cnt[i] : 0;
    s[t] = c;
    __syncthreads();
    for (int off = 1; off < 1024; off <<= 1) {
        int u = (t >= off) ? s[t - off] : 0;
        __syncthreads();
        s[t] += u;
        __syncthreads();
    }
    if (i < NNODES) {
        int excl = s[t] - c + boff[b];
        rowptr[i] = excl;
        cursor[i] = excl;
        float di = rsqrtf((float)c + 1.0f);
        xd4[i] = make_float4(x[3 * i], x[3 * i + 1], x[3 * i + 2], di);
        if (i == NNODES - 1) rowptr[NNODES] = NEDGES;
    }
}

// ---------------- K3: XCD-partitioned scatter into CSR slots ----------------
__global__ __launch_bounds__(256) void k_fill(const int* __restrict__ ei,
                                              int* __restrict__ cursor,
                                              int* __restrict__ slot) {
    int part  = blockIdx.x & (NPART - 1);
    int chunk = blockIdx.x >> 3;
    int base  = chunk * FCHUNK;
    int end   = base + FCHUNK;
    int clo   = part * PSIZE;
    int chi   = clo + PSIZE;
    for (int e = base + threadIdx.x; e < end; e += 256) {
        int c = ei[NEDGES + e];
        if (c >= clo && c < chi) {
            int r = ei[e];
            slot[atomicAdd(&cursor[c], 1)] = r;
        }
    }
}

// ---------------- K4: a4[i]; 8-deep unclamped gather pipeline ----------------
__global__ void k_a(const int* __restrict__ rowptr, const int* __restrict__ cnt,
                    const int* __restrict__ slot, const float4* __restrict__ xd4,
                    float4* __restrict__ a4) {
    int i = blockIdx.x * blockDim.x + threadIdx.x;
    if (i >= NNODES) return;
    int s = rowptr[i], d = cnt[i];
    float ax = 0.f, ay = 0.f, az = 0.f;
    for (int k = 0; k < d; k += 8) {
        float4 xr[8];
        #pragma unroll
        for (int j = 0; j < 8; ++j) xr[j] = xd4[slot[s + k + j]];  // pad-safe
        #pragma unroll
        for (int j = 0; j < 8; ++j) {
            float u = (k + j < d) ? xr[j].w : 0.f;
            ax += u * xr[j].x; ay += u * xr[j].y; az += u * xr[j].z;
        }
    }
    float4 xi = xd4[i];
    float di = xi.w;
    a4[i] = make_float4(di * (ax + di * xi.x),
                        di * (ay + di * xi.y),
                        di * (az + di * xi.z), di);
}

// ---------------- K4b (path A): g1[i][f] = dinv_i * relu(a_i . W1col_f + b1_f) -----
__global__ __launch_bounds__(256) void k_g1(const float4* __restrict__ a4,
                                            const float* __restrict__ W1,
                                            const float* __restrict__ b1,
                                            float* __restrict__ g1) {
    int t = blockIdx.x * blockDim.x + threadIdx.x;   // t = i*64 + f
    int i = t >> 6, f = t & 63;
    if (i >= NNODES) return;
    float4 ai = a4[i];
    float h = fmaxf(ai.x * W1[f] + ai.y * W1[64 + f] + ai.z * W1[128 + f] + b1[f], 0.f);
    g1[t] = ai.w * h;
}

// ---------------- K5A: per-graph; per-lane coalesced g1 gather; inline head --------
__global__ __launch_bounds__(256, 4) void k_fusedA(
    const int* __restrict__ rowptr, const int* __restrict__ slot,
    const float* __restrict__ g1, const float4* __restrict__ a4,
    const float* __restrict__ mv,
    const float* __restrict__ W2, const float* __restrict__ b2,
    const float* __restrict__ Wc1, const float* __restrict__ bc1,
    const float* __restrict__ Wc2, const float* __restrict__ bc2,
    float* __restrict__ out)
{
    __shared__ float aggh[NPG * 65];   // 26 KB
    __shared__ float pools[4 * 128];
    __shared__ float zbuf[160];
    __shared__ float zz[64];

    int g = blockIdx.x;
    int t = threadIdx.x;
    int wb = __builtin_amdgcn_readfirstlane(t >> 6);   // wave id, provably uniform
    int lane = t & 63;

    // ---- phase 1: 25 nodes/wave; edges streamed 16-deep, 1 coalesced load each ----
    for (int i = 0; i < 25; ++i) {
        int n = wb * 25 + i;
        int node = g * NPG + n;
        int s = rowptr[node];
        int d = rowptr[node + 1] - s;
        float acc0 = 0.f, acc1 = 0.f;
        for (int k = 0; k < d; k += 16) {
            float v[16];
            #pragma unroll
            for (int j = 0; j < 16; ++j) {
                int r = slot[s + k + j];           // uniform addr -> s_load, pad-safe
                v[j] = g1[r * 64 + lane];          // coalesced 256B/wave VMEM
            }
            #pragma unroll
            for (int j = 0; j < 16; ++j) {
                float u = (k + j < d) ? 1.f : 0.f; // wave-uniform mask
                if (j & 1) acc1 = fmaf(u, v[j], acc1);
                else       acc0 = fmaf(u, v[j], acc0);
            }
        }
        float selfv = g1[node * 64 + lane];
        float dc = a4[node].w;
        aggh[n * 65 + lane] = dc * (acc0 + acc1 + selfv);
    }
    // no barrier: phase 2 reads only rows this wave wrote

    // ---- phase 2: [25][64] @ [64][128] reg-blocked, W2 streamed from L2 ----
    float2 b2v = *(const float2*)&b2[2 * lane];
    float pool0 = 0.f, pool1 = 0.f;
    {   // half A: i = 0..12
        float acc0[13], acc1[13];
        #pragma unroll
        for (int i = 0; i < 13; ++i) { acc0[i] = 0.f; acc1[i] = 0.f; }
        float2 wv0 = *(const float2*)&W2[2 * lane];
        float2 wv1 = *(const float2*)&W2[128 + 2 * lane];
        for (int f = 0; f < 64; ++f) {
            float2 wnx = (f + 2 < 64) ? *(const float2*)&W2[(f + 2) * 128 + 2 * lane] : wv0;
            #pragma unroll
            for (int i = 0; i < 13; ++i) {
                float rv = aggh[(wb * 25 + i) * 65 + f];   // LDS broadcast
                acc0[i] += rv * wv0.x;
                acc1[i] += rv * wv0.y;
            }
            wv0 = wv1; wv1 = wnx;
        }
        #pragma unroll
        for (int i = 0; i < 13; ++i) {
            pool0 += fmaxf(acc0[i] + b2v.x, 0.f);
            pool1 += fmaxf(acc1[i] + b2v.y, 0.f);
        }
    }
    {   // half B: i = 13..24
        float acc0[12], acc1[12];
        #pragma unroll
        for (int i = 0; i < 12; ++i) { acc0[i] = 0.f; acc1[i] = 0.f; }
        float2 wv0 = *(const float2*)&W2[2 * lane];
        float2 wv1 = *(const float2*)&W2[128 + 2 * lane];
        for (int f = 0; f < 64; ++f) {
            float2 wnx = (f + 2 < 64) ? *(const float2*)&W2[(f + 2) * 128 + 2 * lane] : wv0;
            #pragma unroll
            for (int i = 0; i < 12; ++i) {
                float rv = aggh[(wb * 25 + 13 + i) * 65 + f];
                acc0[i] += rv * wv0.x;
                acc1[i] += rv * wv0.y;
            }
            wv0 = wv1; wv1 = wnx;
        }
        #pragma unroll
        for (int i = 0; i < 12; ++i) {
            pool0 += fmaxf(acc0[i] + b2v.x, 0.f);
            pool1 += fmaxf(acc1[i] + b2v.y, 0.f);
        }
    }

    pools[wb * 128 + 2 * lane]     = pool0;
    pools[wb * 128 + 2 * lane + 1] = pool1;
    __syncthreads();
    if (t < 128)
        zbuf[t] = (pools[t] + pools[128 + t] + pools[256 + t] + pools[384 + t]) * (1.0f / NPG);
    if (t < MDIM) zbuf[128 + t] = mv[g * MDIM + t];
    __syncthreads();
    if (t < 64) {
        float v = bc1[t];
        for (int k = 0; k < 160; ++k) v += zbuf[k] * Wc1[k * 64 + t];
        zz[t] = fmaxf(v, 0.f);
    }
    __syncthreads();
    if (t < NCDIM) {
        float o = bc2[t];
        #pragma unroll
        for (int k = 0; k < 64; ++k) o += zz[k] * Wc2[k * NCDIM + t];
        out[g * NCDIM + t] = o;
    }
}

// ---------------- K5B: round-10 fused (half-graph, readlane s_load gather) ---------
__global__ __launch_bounds__(256, 4) void k_fusedB(
    const int* __restrict__ rowptr, const int* __restrict__ cnt,
    const int* __restrict__ slot, const float4* __restrict__ a4,
    const float* __restrict__ W1, const float* __restrict__ b1,
    const float* __restrict__ W2, const float* __restrict__ b2,
    float* __restrict__ pp)
{
    __shared__ float aggh[52 * 65];
    __shared__ float pools[4 * 128];

    int b = blockIdx.x;
    int g = b >> 1, half = b & 1;
    int t = threadIdx.x;
    int w = t >> 6;
    int lane = t & 63;

    float w10 = W1[lane], w11 = W1[64 + lane], w12 = W1[128 + lane], b1f = b1[lane];
    int nn = (w < 2) ? 13 : 12;

    for (int i = 0; i < nn; ++i) {
        int n = w + 4 * i;
        int node = g * NPG + half * HALF + n;
        int s = rowptr[node], d = cnt[node];
        float acc = 0.f;
        for (int base = 0; base < d; base += 64) {
            int m = min(64, d - base);
            int sl = (lane < m) ? slot[s + base + lane] : 0;
            for (int k0 = 0; k0 < m; k0 += 8) {
                float4 pre[8];
                #pragma unroll
                for (int j = 0; j < 8; ++j) {
                    int kk = min(k0 + j, m - 1);
                    int rr = __builtin_amdgcn_readlane(sl, kk);
                    pre[j] = a4[rr];
                }
                #pragma unroll
                for (int j = 0; j < 8; ++j) {
                    if (k0 + j < m) {
                        float4 ar = pre[j];
                        float h = fmaxf(ar.x * w10 + ar.y * w11 + ar.z * w12 + b1f, 0.f);
                        acc += ar.w * h;
                    }
                }
            }
        }
        float4 ai = a4[node];
        float hs = fmaxf(ai.x * w10 + ai.y * w11 + ai.z * w12 + b1f, 0.f);
        aggh[n * 65 + lane] = ai.w * (acc + ai.w * hs);
    }

    float2 b2v = *(const float2*)&b2[2 * lane];
    float acc0[13], acc1[13];
    #pragma unroll
    for (int i = 0; i < 13; ++i) { acc0[i] = 0.f; acc1[i] = 0.f; }
    {
        float2 wv0 = *(const float2*)&W2[2 * lane];
        float2 wv1 = *(const float2*)&W2[128 + 2 * lane];
        for (int f = 0; f < 64; ++f) {
            float2 wnx = (f + 2 < 64) ? *(const float2*)&W2[(f + 2) * 128 + 2 * lane] : wv0;
            #pragma unroll
            for (int i = 0; i < 13; ++i) {
                float rv = (i < nn) ? aggh[(w + 4 * i) * 65 + f] : 0.f;
                acc0[i] += rv * wv0.x;
                acc1[i] += rv * wv0.y;
            }
            wv0 = wv1; wv1 = wnx;
        }
    }
    float pool0 = 0.f, pool1 = 0.f;
    #pragma unroll
    for (int i = 0; i < 13; ++i) {
        if (i < nn) {
            pool0 += fmaxf(acc0[i] + b2v.x, 0.f);
            pool1 += fmaxf(acc1[i] + b2v.y, 0.f);
        }
    }
    pools[w * 128 + 2 * lane]     = pool0;
    pools[w * 128 + 2 * lane + 1] = pool1;
    __syncthreads();
    if (t < 128)
        pp[b * 128 + t] = pools[t] + pools[128 + t] + pools[256 + t] + pools[384 + t];
}

// ---------------- K6B: merge half-graph pools + MLP head ----------------
__global__ __launch_bounds__(128) void k_head(
    const float* __restrict__ pp, const float* __restrict__ mv,
    const float* __restrict__ Wc1, const float* __restrict__ bc1,
    const float* __restrict__ Wc2, const float* __restrict__ bc2,
    float* __restrict__ out)
{
    __shared__ float zbuf[160];
    __shared__ float zz[64];
    int g = blockIdx.x;
    int t = threadIdx.x;
    if (t < 128)
        zbuf[t] = (pp[(2 * g) * 128 + t] + pp[(2 * g + 1) * 128 + t]) * (1.0f / NPG);
    if (t < MDIM) zbuf[128 + t] = mv[g * MDIM + t];
    __syncthreads();
    if (t < 64) {
        float v = bc1[t];
        for (int k = 0; k < 160; ++k) v += zbuf[k] * Wc1[k * 64 + t];
        zz[t] = fmaxf(v, 0.f);
    }
    __syncthreads();
    if (t < NCDIM) {
        float o = bc2[t];
        #pragma unroll
        for (int k = 0; k < 64; ++k) o += zz[k] * Wc2[k * NCDIM + t];
        out[g * NCDIM + t] = o;
    }
}

extern "C" void kernel_launch(void* const* d_in, const int* in_sizes, int n_in,
                              void* d_out, int out_size, void* d_ws, size_t ws_size,
                              hipStream_t stream) {
    const float* x   = (const float*)d_in[0];
    const int*   ei  = (const int*)d_in[1];   // int64 in ref -> int32 on device
    const float* mv  = (const float*)d_in[3];
    const float* W1  = (const float*)d_in[4];
    const float* b1  = (const float*)d_in[5];
    const float* W2  = (const float*)d_in[6];
    const float* b2  = (const float*)d_in[7];
    const float* Wc1 = (const float*)d_in[8];
    const float* bc1 = (const float*)d_in[9];
    const float* Wc2 = (const float*)d_in[10];
    const float* bc2 = (const float*)d_in[11];
    float* out = (float*)d_out;
    float* ws  = (float*)d_ws;

    const int* col = ei + NEDGES;
    bool bigws = ws_size >= (size_t)WS_A * sizeof(float);

    if (bigws) {
        // ---------------- Path A: g1-gather design ----------------
        int*    rowptr = (int*)(ws + A_ROWPTR);
        float4* a4     = (float4*)(ws + A_A4);
        int*    slot   = (int*)(ws + A_SLOT);
        float*  g1     = ws + A_G1;
        int*    cnt    = (int*)(ws + A_CNT);     // aliases g1 (dead before k_g1)
        int*    cursor = (int*)(ws + A_CURSOR);
        float4* xd4    = (float4*)(ws + A_XD4);
        int*    bsum   = (int*)(ws + A_BSUM);
        int*    boff   = (int*)(ws + A_BOFF);

        hipMemsetAsync(cnt, 0, (size_t)NNODES * sizeof(int), stream);
        hipMemsetAsync(slot + NEDGES, 0, 64 * sizeof(int), stream);

        k_count<<<FBLKS * NPART, 256, 0, stream>>>(col, cnt);
        k_bsum <<<NB, 1024, 0, stream>>>(cnt, bsum);
        k_bscan<<<1, 128, 0, stream>>>(bsum, boff);
        k_scan2<<<NB, 1024, 0, stream>>>(cnt, boff, x, rowptr, cursor, xd4);
        k_fill <<<FBLKS * NPART, 256, 0, stream>>>(ei, cursor, slot);
        k_a    <<<(NNODES + 255) / 256, 256, 0, stream>>>(rowptr, cnt, slot, xd4, a4);
        k_g1   <<<(NNODES * 64) / 256, 256, 0, stream>>>(a4, W1, b1, g1);
        k_fusedA<<<NGRAPH, 256, 0, stream>>>(rowptr, slot, g1, a4, mv,
                                             W2, b2, Wc1, bc1, Wc2, bc2, out);
    } else {
        // ---------------- Path B: round-10 proven design ----------------
        if (ws_size < (size_t)WS_B * sizeof(float)) return;
        float4* xd4    = (float4*)(ws + B_XD4);
        float4* a4     = (float4*)(ws + B_A4);
        int*    cnt    = (int*)(ws + B_CNT);
        int*    rowptr = (int*)(ws + B_ROWPTR);
        int*    cursor = (int*)(ws + B_CURSOR);
        int*    bsum   = (int*)(ws + B_BSUM);
        int*    boff   = (int*)(ws + B_BOFF);
        int*    slot   = (int*)(ws + B_SLOT);
        float*  pp     = ws + B_PP;

        hipMemsetAsync(cnt, 0, (size_t)NNODES * sizeof(int), stream);
        hipMemsetAsync(slot + NEDGES, 0, 64 * sizeof(int), stream);

        k_count<<<FBLKS * NPART, 256, 0, stream>>>(col, cnt);
        k_bsum <<<NB, 1024, 0, stream>>>(cnt, bsum);
        k_bscan<<<1, 128, 0, stream>>>(bsum, boff);
        k_scan2<<<NB, 1024, 0, stream>>>(cnt, boff, x, rowptr, cursor, xd4);
        k_fill <<<FBLKS * NPART, 256, 0, stream>>>(ei, cursor, slot);
        k_a    <<<(NNODES + 255) / 256, 256, 0, stream>>>(rowptr, cnt, slot, xd4, a4);
        k_fusedB<<<2 * NGRAPH, 256, 0, stream>>>(rowptr, cnt, slot, a4,
                                                 W1, b1, W2, b2, pp);
        k_head <<<NGRAPH, 128, 0, stream>>>(pp, mv, Wc1, bc1, Wc2, bc2, out);
    }
}

// Round 13
// 445.848 us; speedup vs baseline: 1.1730x; 1.0697x over previous
//
#include <hip/hip_runtime.h>
#include <hip/hip_fp16.h>

#define NNODES 100000
#define NEDGES 3200000
#define NGRAPH 1000
#define NPG    100
#define MDIM   32
#define NCDIM  10
#define NB     98          // ceil(NNODES/1024) scan blocks

#define NPART   8          // scatter partitions (== XCD count)
#define PSIZE   12500      // nodes per partition
#define FCHUNK  6250       // edges per chunk
#define FBLKS   (NEDGES / FCHUNK)   // 512 chunks

// ws layout (float units), no aliasing, total 30.0 MB (ws >= 40.4 MB proven r12):
#define A_ROWPTR 0          // 100032 ints
#define A_A4     100032     // 100000 float4
#define A_SLOT   500032     // 3200064 ints (64 pad)
#define A_G1H    3700096    // 3200000 uints (= 6.4M halfs, [node][64] fp16)
#define A_CNT    6900096    // 100000 ints
#define A_CURSOR 7000096    // 100000 ints
#define A_XD4    7100096    // 100000 float4
#define A_BSUM   7500096    // 128 ints
#define A_BOFF   7500224    // 128 ints
#define WS_FLOATS 7500352   // 30.0 MB

// ---------------- K1: in-degree histogram, XCD-partitioned ----------------
__global__ __launch_bounds__(256) void k_count(const int* __restrict__ col,
                                               int* __restrict__ cnt) {
    int part  = blockIdx.x & (NPART - 1);
    int chunk = blockIdx.x >> 3;
    int base  = chunk * FCHUNK;
    int end   = base + FCHUNK;
    int clo   = part * PSIZE;
    int chi   = clo + PSIZE;
    for (int e = base + threadIdx.x; e < end; e += 256) {
        int c = col[e];
        if (c >= clo && c < chi) atomicAdd(&cnt[c], 1);
    }
}

// ---------------- K2a: per-block sums of cnt ----------------
__global__ __launch_bounds__(1024) void k_bsum(const int* __restrict__ cnt,
                                               int* __restrict__ bsum) {
    __shared__ int wsum[16];
    int b = blockIdx.x, t = threadIdx.x;
    int i = b * 1024 + t;
    int v = (i < NNODES) ? cnt[i] : 0;
    for (int off = 32; off; off >>= 1) v += __shfl_down(v, off);
    if ((t & 63) == 0) wsum[t >> 6] = v;
    __syncthreads();
    if (t < 16) {
        int s = wsum[t];
        for (int off = 8; off; off >>= 1) s += __shfl_down(s, off);
        if (t == 0) bsum[b] = s;
    }
}

// ---------------- K2b: exclusive scan of NB block sums ----------------
__global__ void k_bscan(const int* __restrict__ bsum, int* __restrict__ boff) {
    __shared__ int s[128];
    int t = threadIdx.x;
    int v = (t < NB) ? bsum[t] : 0;
    s[t] = v;
    __syncthreads();
    for (int off = 1; off < 128; off <<= 1) {
        int u = (t >= off) ? s[t - off] : 0;
        __syncthreads();
        s[t] += u;
        __syncthreads();
    }
    if (t < NB) boff[t] = s[t] - v;   // exclusive
}

// ---------------- K2c: block-local scan + offsets; also xd4/cursor ----------------
__global__ __launch_bounds__(1024) void k_scan2(const int* __restrict__ cnt,
                                                const int* __restrict__ boff,
                                                const float* __restrict__ x,
                                                int* __restrict__ rowptr,
                                                int* __restrict__ cursor,
                                                float4* __restrict__ xd4) {
    __shared__ int s[1024];
    int b = blockIdx.x, t = threadIdx.x;
    int i = b * 1024 + t;
    int c = (i < NNODES) ? cnt[i] : 0;
    s[t] = c;
    __syncthreads();
    for (int off = 1; off < 1024; off <<= 1) {
        int u = (t >= off) ? s[t - off] : 0;
        __syncthreads();
        s[t] += u;
        __syncthreads();
    }
    if (i < NNODES) {
        int excl = s[t] - c + boff[b];
        rowptr[i] = excl;
        cursor[i] = excl;
        float di = rsqrtf((float)c + 1.0f);
        xd4[i] = make_float4(x[3 * i], x[3 * i + 1], x[3 * i + 2], di);
        if (i == NNODES - 1) rowptr[NNODES] = NEDGES;
    }
}

// ---------------- K3: XCD-partitioned scatter into CSR slots ----------------
__global__ __launch_bounds__(256) void k_fill(const int* __restrict__ ei,
                                              int* __restrict__ cursor,
                                              int* __restrict__ slot) {
    int part  = blockIdx.x & (NPART - 1);
    int chunk = blockIdx.x >> 3;
    int base  = chunk * FCHUNK;
    int end   = base + FCHUNK;
    int clo   = part * PSIZE;
    int chi   = clo + PSIZE;
    for (int e = base + threadIdx.x; e < end; e += 256) {
        int c = ei[NEDGES + e];
        if (c >= clo && c < chi) {
            int r = ei[e];
            slot[atomicAdd(&cursor[c], 1)] = r;
        }
    }
}

// ---------------- K4: a4[i]; 8-deep unclamped gather pipeline ----------------
__global__ void k_a(const int* __restrict__ rowptr, const int* __restrict__ cnt,
                    const int* __restrict__ slot, const float4* __restrict__ xd4,
                    float4* __restrict__ a4) {
    int i = blockIdx.x * blockDim.x + threadIdx.x;
    if (i >= NNODES) return;
    int s = rowptr[i], d = cnt[i];
    float ax = 0.f, ay = 0.f, az = 0.f;
    for (int k = 0; k < d; k += 8) {
        float4 xr[8];
        #pragma unroll
        for (int j = 0; j < 8; ++j) xr[j] = xd4[slot[s + k + j]];  // pad-safe
        #pragma unroll
        for (int j = 0; j < 8; ++j) {
            float u = (k + j < d) ? xr[j].w : 0.f;
            ax += u * xr[j].x; ay += u * xr[j].y; az += u * xr[j].z;
        }
    }
    float4 xi = xd4[i];
    float di = xi.w;
    a4[i] = make_float4(di * (ax + di * xi.x),
                        di * (ay + di * xi.y),
                        di * (az + di * xi.z), di);
}

// ---------------- K4b: g1h[i][2j:2j+1] = fp16( dinv_i * relu(a_i.W1col + b1) ) -----
__global__ __launch_bounds__(256) void k_g1(const float4* __restrict__ a4,
                                            const float* __restrict__ W1,
                                            const float* __restrict__ b1,
                                            unsigned int* __restrict__ g1h) {
    int t = blockIdx.x * blockDim.x + threadIdx.x;   // t = i*32 + j
    int i = t >> 5, j = t & 31;
    if (i >= NNODES) return;
    float4 ai = a4[i];
    int f0 = 2 * j, f1 = f0 + 1;
    float h0 = fmaxf(ai.x * W1[f0] + ai.y * W1[64 + f0] + ai.z * W1[128 + f0] + b1[f0], 0.f);
    float h1 = fmaxf(ai.x * W1[f1] + ai.y * W1[64 + f1] + ai.z * W1[128 + f1] + b1[f1], 0.f);
    __half2 hv = __floats2half2_rn(ai.w * h0, ai.w * h1);
    g1h[t] = *(unsigned int*)&hv;
}

// ---------------- K5: per-graph; fp16 2-edges-per-load gather; inline head ---------
__global__ __launch_bounds__(256, 4) void k_fusedA(
    const int* __restrict__ rowptr, const int* __restrict__ slot,
    const unsigned int* __restrict__ g1h, const float4* __restrict__ a4,
    const float* __restrict__ mv,
    const float* __restrict__ W2, const float* __restrict__ b2,
    const float* __restrict__ Wc1, const float* __restrict__ bc1,
    const float* __restrict__ Wc2, const float* __restrict__ bc2,
    float* __restrict__ out)
{
    __shared__ float aggh[NPG * 66];   // 26.4 KB, even pad -> aligned float2 rows
    __shared__ float pools[4 * 128];
    __shared__ float zbuf[160];
    __shared__ float zz[64];

    int g = blockIdx.x;
    int t = threadIdx.x;
    int wb = t >> 6;           // wave 0..3; owns nodes wb*25 .. wb*25+24
    int lane = t & 63;
    int h = lane >> 5;         // which edge of the pair this half-wave handles
    int j = lane & 31;         // feature-pair index (features 2j, 2j+1)

    // ---- phase 1: per-node aggregation; 256B wave-load covers TWO edges ----
    for (int i = 0; i < 25; ++i) {
        int n = wb * 25 + i;
        int node = g * NPG + n;
        int s = rowptr[node];
        int d = rowptr[node + 1] - s;
        float acc0 = 0.f, acc1 = 0.f;
        for (int k0 = 0; k0 < d; k0 += 16) {
            int rr[8];
            #pragma unroll
            for (int jj = 0; jj < 8; ++jj)
                rr[jj] = slot[s + k0 + 2 * jj + h];       // 2 words/wave, pad-safe
            #pragma unroll
            for (int jj = 0; jj < 8; ++jj) {
                unsigned int v = g1h[rr[jj] * 32 + j];    // coalesced 256B/wave
                float2 f = __half22float2(*(__half2*)&v);
                bool ok = (k0 + 2 * jj + h) < d;          // uniform per half-wave
                acc0 += ok ? f.x : 0.f;
                acc1 += ok ? f.y : 0.f;
            }
        }
        acc0 += __shfl_xor(acc0, 32);                     // combine edge-halves
        acc1 += __shfl_xor(acc1, 32);
        if (h == 0) {
            unsigned int sv = g1h[node * 32 + j];
            float2 sf = __half22float2(*(__half2*)&sv);
            float dc = a4[node].w;
            *(float2*)&aggh[n * 66 + 2 * j] =
                make_float2(dc * (acc0 + sf.x), dc * (acc1 + sf.y));
        }
    }
    // no barrier: phase 2 reads only rows this wave wrote (same-wave lgkmcnt)

    // ---- phase 2: [25][64] @ [64][128] reg-blocked, W2 streamed from L2 ----
    float2 b2v = *(const float2*)&b2[2 * lane];
    float pool0 = 0.f, pool1 = 0.f;
    {   // half A: i = 0..12
        float acc0[13], acc1[13];
        #pragma unroll
        for (int i = 0; i < 13; ++i) { acc0[i] = 0.f; acc1[i] = 0.f; }
        float2 wv0 = *(const float2*)&W2[2 * lane];
        float2 wv1 = *(const float2*)&W2[128 + 2 * lane];
        for (int f = 0; f < 64; ++f) {
            float2 wnx = (f + 2 < 64) ? *(const float2*)&W2[(f + 2) * 128 + 2 * lane] : wv0;
            #pragma unroll
            for (int i = 0; i < 13; ++i) {
                float rv = aggh[(wb * 25 + i) * 66 + f];   // LDS broadcast
                acc0[i] += rv * wv0.x;
                acc1[i] += rv * wv0.y;
            }
            wv0 = wv1; wv1 = wnx;
        }
        #pragma unroll
        for (int i = 0; i < 13; ++i) {
            pool0 += fmaxf(acc0[i] + b2v.x, 0.f);
            pool1 += fmaxf(acc1[i] + b2v.y, 0.f);
        }
    }
    {   // half B: i = 13..24
        float acc0[12], acc1[12];
        #pragma unroll
        for (int i = 0; i < 12; ++i) { acc0[i] = 0.f; acc1[i] = 0.f; }
        float2 wv0 = *(const float2*)&W2[2 * lane];
        float2 wv1 = *(const float2*)&W2[128 + 2 * lane];
        for (int f = 0; f < 64; ++f) {
            float2 wnx = (f + 2 < 64) ? *(const float2*)&W2[(f + 2) * 128 + 2 * lane] : wv0;
            #pragma unroll
            for (int i = 0; i < 12; ++i) {
                float rv = aggh[(wb * 25 + 13 + i) * 66 + f];
                acc0[i] += rv * wv0.x;
                acc1[i] += rv * wv0.y;
            }
            wv0 = wv1; wv1 = wnx;
        }
        #pragma unroll
        for (int i = 0; i < 12; ++i) {
            pool0 += fmaxf(acc0[i] + b2v.x, 0.f);
            pool1 += fmaxf(acc1[i] + b2v.y, 0.f);
        }
    }

    pools[wb * 128 + 2 * lane]     = pool0;
    pools[wb * 128 + 2 * lane + 1] = pool1;
    __syncthreads();
    if (t < 128)
        zbuf[t] = (pools[t] + pools[128 + t] + pools[256 + t] + pools[384 + t]) * (1.0f / NPG);
    if (t < MDIM) zbuf[128 + t] = mv[g * MDIM + t];
    __syncthreads();
    if (t < 64) {
        float v = bc1[t];
        for (int k = 0; k < 160; ++k) v += zbuf[k] * Wc1[k * 64 + t];
        zz[t] = fmaxf(v, 0.f);
    }
    __syncthreads();
    if (t < NCDIM) {
        float o = bc2[t];
        #pragma unroll
        for (int k = 0; k < 64; ++k) o += zz[k] * Wc2[k * NCDIM + t];
        out[g * NCDIM + t] = o;
    }
}

extern "C" void kernel_launch(void* const* d_in, const int* in_sizes, int n_in,
                              void* d_out, int out_size, void* d_ws, size_t ws_size,
                              hipStream_t stream) {
    const float* x   = (const float*)d_in[0];
    const int*   ei  = (const int*)d_in[1];   // int64 in ref -> int32 on device
    const float* mv  = (const float*)d_in[3];
    const float* W1  = (const float*)d_in[4];
    const float* b1  = (const float*)d_in[5];
    const float* W2  = (const float*)d_in[6];
    const float* b2  = (const float*)d_in[7];
    const float* Wc1 = (const float*)d_in[8];
    const float* bc1 = (const float*)d_in[9];
    const float* Wc2 = (const float*)d_in[10];
    const float* bc2 = (const float*)d_in[11];
    float* out = (float*)d_out;
    float* ws  = (float*)d_ws;

    if (ws_size < (size_t)WS_FLOATS * sizeof(float)) return;  // proven available r12

    int*          rowptr = (int*)(ws + A_ROWPTR);
    float4*       a4     = (float4*)(ws + A_A4);
    int*          slot   = (int*)(ws + A_SLOT);
    unsigned int* g1h    = (unsigned int*)(ws + A_G1H);
    int*          cnt    = (int*)(ws + A_CNT);
    int*          cursor = (int*)(ws + A_CURSOR);
    float4*       xd4    = (float4*)(ws + A_XD4);
    int*          bsum   = (int*)(ws + A_BSUM);
    int*          boff   = (int*)(ws + A_BOFF);

    hipMemsetAsync(cnt, 0, (size_t)NNODES * sizeof(int), stream);
    hipMemsetAsync(slot + NEDGES, 0, 64 * sizeof(int), stream);

    const int* col = ei + NEDGES;

    k_count<<<FBLKS * NPART, 256, 0, stream>>>(col, cnt);
    k_bsum <<<NB, 1024, 0, stream>>>(cnt, bsum);
    k_bscan<<<1, 128, 0, stream>>>(bsum, boff);
    k_scan2<<<NB, 1024, 0, stream>>>(cnt, boff, x, rowptr, cursor, xd4);
    k_fill <<<FBLKS * NPART, 256, 0, stream>>>(ei, cursor, slot);
    k_a    <<<(NNODES + 255) / 256, 256, 0, stream>>>(rowptr, cnt, slot, xd4, a4);
    k_g1   <<<(NNODES * 32) / 256, 256, 0, stream>>>(a4, W1, b1, g1h);
    k_fusedA<<<NGRAPH, 256, 0, stream>>>(rowptr, slot, g1h, a4, mv,
                                         W2, b2, Wc1, bc1, Wc2, bc2, out);
}

// Round 14
// 358.454 us; speedup vs baseline: 1.4590x; 1.2438x over previous
//
#include <hip/hip_runtime.h>
#include <hip/hip_fp16.h>

#define NNODES 100000
#define NEDGES 3200000
#define NGRAPH 1000
#define NPG    100
#define MDIM   32
#define NCDIM  10

#define CAP     48         // bucket capacity; P(deg>48)~1.8e-3/node -> ~200 ovf edges
#define OVF_CAP 4096

#define NPART   8          // scatter partitions (== XCD count)
#define PSIZE   12500      // nodes per partition
#define FCHUNK  6250       // edges per chunk
#define FBLKS   (NEDGES / FCHUNK)   // 512 chunks

// ws layout (float units), total 36.0 MB (ws >= 40.4 MB proven in r12):
#define W_S2    0           // slot2: 100000*48 + 64 pad ints
#define W_CNT   4800064     // 100000 ints
#define W_DINV  4900064     // 100000 floats
#define W_XD4   5000064     // 100000 float4 (16B aligned)
#define W_A4    5400064     // 100000 float4
#define W_G1H   5800064     // 3200000 uints ([node][32] half2)
#define W_OVF   9000064     // 1 + 2*4096 ints
#define WS_FLOATS 9008257   // 36.0 MB

// ---------------- K1: bucket fill, XCD-partitioned; builds cnt on the fly ---------
__global__ __launch_bounds__(256) void k_fillbkt(const int* __restrict__ ei,
                                                 int* __restrict__ cnt,
                                                 int* __restrict__ slot2,
                                                 int* __restrict__ ovf) {
    int part  = blockIdx.x & (NPART - 1);
    int chunk = blockIdx.x >> 3;
    int base  = chunk * FCHUNK;
    int end   = base + FCHUNK;
    int clo   = part * PSIZE;
    int chi   = clo + PSIZE;
    for (int e = base + threadIdx.x; e < end; e += 256) {
        int c = ei[NEDGES + e];
        if (c >= clo && c < chi) {
            int r = ei[e];
            int idx = atomicAdd(&cnt[c], 1);
            if (idx < CAP) {
                slot2[c * CAP + idx] = r;
            } else {
                int o = atomicAdd(&ovf[0], 1);
                if (o < OVF_CAP) { ovf[1 + 2 * o] = r; ovf[2 + 2 * o] = c; }
            }
        }
    }
}

// ---------------- K2: dinv + packed xd4 from final cnt ----------------
__global__ __launch_bounds__(256) void k_prep(const int* __restrict__ cnt,
                                              const float* __restrict__ x,
                                              float* __restrict__ dinv,
                                              float4* __restrict__ xd4) {
    int i = blockIdx.x * blockDim.x + threadIdx.x;
    if (i >= NNODES) return;
    float di = rsqrtf((float)cnt[i] + 1.0f);
    dinv[i] = di;
    xd4[i] = make_float4(x[3 * i], x[3 * i + 1], x[3 * i + 2], di);
}

// ---------------- K3: a4[i] from bucket; 8-deep clamped gather pipeline -----------
__global__ void k_a(const int* __restrict__ cnt, const int* __restrict__ slot2,
                    const float4* __restrict__ xd4, float4* __restrict__ a4) {
    int i = blockIdx.x * blockDim.x + threadIdx.x;
    if (i >= NNODES) return;
    int d = min(cnt[i], CAP);
    int s = i * CAP;
    float ax = 0.f, ay = 0.f, az = 0.f;
    for (int k = 0; k < d; k += 8) {
        float4 xr[8];
        #pragma unroll
        for (int j = 0; j < 8; ++j) {
            int idx = slot2[s + k + j];              // may be garbage past d
            xr[j] = xd4[(k + j < d) ? idx : 0];      // clamp before gather
        }
        #pragma unroll
        for (int j = 0; j < 8; ++j) {
            float u = (k + j < d) ? xr[j].w : 0.f;
            ax += u * xr[j].x; ay += u * xr[j].y; az += u * xr[j].z;
        }
    }
    float4 xi = xd4[i];
    float di = xi.w;
    a4[i] = make_float4(di * (ax + di * xi.x),
                        di * (ay + di * xi.y),
                        di * (az + di * xi.z), di);
}

// ---------------- K3b: exact fixup of a4 for overflow edges (tiny) ----------------
__global__ void k_ovfA(const int* __restrict__ ovf, const float4* __restrict__ xd4,
                       const float* __restrict__ dinv, float* __restrict__ a4f) {
    int n = min(ovf[0], OVF_CAP);
    for (int k = threadIdx.x; k < n; k += 256) {
        int r = ovf[1 + 2 * k];
        int c = ovf[2 + 2 * k];
        float4 xr = xd4[r];
        float s = dinv[c] * xr.w;
        atomicAdd(&a4f[c * 4 + 0], s * xr.x);
        atomicAdd(&a4f[c * 4 + 1], s * xr.y);
        atomicAdd(&a4f[c * 4 + 2], s * xr.z);
    }
}

// ---------------- K4: g1h[i][2j:2j+1] = fp16( dinv_i * relu(a_i.W1col + b1) ) -----
__global__ __launch_bounds__(256) void k_g1(const float4* __restrict__ a4,
                                            const float* __restrict__ W1,
                                            const float* __restrict__ b1,
                                            unsigned int* __restrict__ g1h) {
    int t = blockIdx.x * blockDim.x + threadIdx.x;   // t = i*32 + j
    int i = t >> 5, j = t & 31;
    if (i >= NNODES) return;
    float4 ai = a4[i];
    int f0 = 2 * j, f1 = f0 + 1;
    float h0 = fmaxf(ai.x * W1[f0] + ai.y * W1[64 + f0] + ai.z * W1[128 + f0] + b1[f0], 0.f);
    float h1 = fmaxf(ai.x * W1[f1] + ai.y * W1[64 + f1] + ai.z * W1[128 + f1] + b1[f1], 0.f);
    __half2 hv = __floats2half2_rn(ai.w * h0, ai.w * h1);
    g1h[t] = *(unsigned int*)&hv;
}

// ---------------- K5: per-graph; fp16 2-edges-per-load bucket gather; inline head --
__global__ __launch_bounds__(256, 4) void k_fusedA(
    const int* __restrict__ cnt, const int* __restrict__ slot2,
    const int* __restrict__ ovf,
    const unsigned int* __restrict__ g1h, const float* __restrict__ dinv,
    const float* __restrict__ mv,
    const float* __restrict__ W2, const float* __restrict__ b2,
    const float* __restrict__ Wc1, const float* __restrict__ bc1,
    const float* __restrict__ Wc2, const float* __restrict__ bc2,
    float* __restrict__ out)
{
    __shared__ float aggh[NPG * 66];   // 26.4 KB, even pad -> aligned float2 rows
    __shared__ float pools[4 * 128];
    __shared__ float zbuf[160];
    __shared__ float zz[64];

    int g = blockIdx.x;
    int t = threadIdx.x;
    int wb = t >> 6;           // wave 0..3; owns nodes wb*25 .. wb*25+24
    int lane = t & 63;
    int h = lane >> 5;         // which edge of the pair this half-wave handles
    int j = lane & 31;         // feature-pair index (features 2j, 2j+1)

    // ---- phase 1: per-node aggregation; 256B wave-load covers TWO edges ----
    for (int i = 0; i < 25; ++i) {
        int n = wb * 25 + i;
        int node = g * NPG + n;
        int s = node * CAP;
        int d = min(cnt[node], CAP);
        float acc0 = 0.f, acc1 = 0.f;
        for (int k0 = 0; k0 < d; k0 += 16) {
            int rr[8];
            #pragma unroll
            for (int jj = 0; jj < 8; ++jj) {
                int pos = k0 + 2 * jj + h;
                int v = slot2[s + pos];               // may be garbage past d
                rr[jj] = (pos < d) ? v : 0;           // clamp before gather
            }
            #pragma unroll
            for (int jj = 0; jj < 8; ++jj) {
                unsigned int v = g1h[rr[jj] * 32 + j];    // coalesced 256B/wave
                float2 f = __half22float2(*(__half2*)&v);
                bool ok = (k0 + 2 * jj + h) < d;          // uniform per half-wave
                acc0 += ok ? f.x : 0.f;
                acc1 += ok ? f.y : 0.f;
            }
        }
        acc0 += __shfl_xor(acc0, 32);                     // combine edge-halves
        acc1 += __shfl_xor(acc1, 32);
        if (h == 0) {
            unsigned int sv = g1h[node * 32 + j];
            float2 sf = __half22float2(*(__half2*)&sv);
            float dc = dinv[node];
            *(float2*)&aggh[n * 66 + 2 * j] =
                make_float2(dc * (acc0 + sf.x), dc * (acc1 + sf.y));
        }
    }
    // ---- overflow edges (expected ~200 total): exact, wave-local rows ----
    {
        int novf = min(ovf[0], OVF_CAP);
        int glo = g * NPG;
        for (int k = 0; k < novf; ++k) {
            int r = ovf[1 + 2 * k];
            int c = ovf[2 + 2 * k];
            int n = c - glo;
            if (n >= wb * 25 && n < wb * 25 + 25 && h == 0) {
                unsigned int v = g1h[r * 32 + j];
                float2 f = __half22float2(*(__half2*)&v);
                float dc = dinv[c];
                aggh[n * 66 + 2 * j]     += dc * f.x;
                aggh[n * 66 + 2 * j + 1] += dc * f.y;
            }
        }
    }
    // no barrier: phase 2 reads only rows this wave wrote (same-wave lgkmcnt)

    // ---- phase 2: [25][64] @ [64][128] reg-blocked, W2 streamed from L2 ----
    float2 b2v = *(const float2*)&b2[2 * lane];
    float pool0 = 0.f, pool1 = 0.f;
    {   // half A: i = 0..12
        float acc0[13], acc1[13];
        #pragma unroll
        for (int i = 0; i < 13; ++i) { acc0[i] = 0.f; acc1[i] = 0.f; }
        float2 wv0 = *(const float2*)&W2[2 * lane];
        float2 wv1 = *(const float2*)&W2[128 + 2 * lane];
        for (int f = 0; f < 64; ++f) {
            float2 wnx = (f + 2 < 64) ? *(const float2*)&W2[(f + 2) * 128 + 2 * lane] : wv0;
            #pragma unroll
            for (int i = 0; i < 13; ++i) {
                float rv = aggh[(wb * 25 + i) * 66 + f];   // LDS broadcast
                acc0[i] += rv * wv0.x;
                acc1[i] += rv * wv0.y;
            }
            wv0 = wv1; wv1 = wnx;
        }
        #pragma unroll
        for (int i = 0; i < 13; ++i) {
            pool0 += fmaxf(acc0[i] + b2v.x, 0.f);
            pool1 += fmaxf(acc1[i] + b2v.y, 0.f);
        }
    }
    {   // half B: i = 13..24
        float acc0[12], acc1[12];
        #pragma unroll
        for (int i = 0; i < 12; ++i) { acc0[i] = 0.f; acc1[i] = 0.f; }
        float2 wv0 = *(const float2*)&W2[2 * lane];
        float2 wv1 = *(const float2*)&W2[128 + 2 * lane];
        for (int f = 0; f < 64; ++f) {
            float2 wnx = (f + 2 < 64) ? *(const float2*)&W2[(f + 2) * 128 + 2 * lane] : wv0;
            #pragma unroll
            for (int i = 0; i < 12; ++i) {
                float rv = aggh[(wb * 25 + 13 + i) * 66 + f];
                acc0[i] += rv * wv0.x;
                acc1[i] += rv * wv0.y;
            }
            wv0 = wv1; wv1 = wnx;
        }
        #pragma unroll
        for (int i = 0; i < 12; ++i) {
            pool0 += fmaxf(acc0[i] + b2v.x, 0.f);
            pool1 += fmaxf(acc1[i] + b2v.y, 0.f);
        }
    }

    pools[wb * 128 + 2 * lane]     = pool0;
    pools[wb * 128 + 2 * lane + 1] = pool1;
    __syncthreads();
    if (t < 128)
        zbuf[t] = (pools[t] + pools[128 + t] + pools[256 + t] + pools[384 + t]) * (1.0f / NPG);
    if (t < MDIM) zbuf[128 + t] = mv[g * MDIM + t];
    __syncthreads();
    if (t < 64) {
        float v = bc1[t];
        for (int k = 0; k < 160; ++k) v += zbuf[k] * Wc1[k * 64 + t];
        zz[t] = fmaxf(v, 0.f);
    }
    __syncthreads();
    if (t < NCDIM) {
        float o = bc2[t];
        #pragma unroll
        for (int k = 0; k < 64; ++k) o += zz[k] * Wc2[k * NCDIM + t];
        out[g * NCDIM + t] = o;
    }
}

extern "C" void kernel_launch(void* const* d_in, const int* in_sizes, int n_in,
                              void* d_out, int out_size, void* d_ws, size_t ws_size,
                              hipStream_t stream) {
    const float* x   = (const float*)d_in[0];
    const int*   ei  = (const int*)d_in[1];   // int64 in ref -> int32 on device
    const float* mv  = (const float*)d_in[3];
    const float* W1  = (const float*)d_in[4];
    const float* b1  = (const float*)d_in[5];
    const float* W2  = (const float*)d_in[6];
    const float* b2  = (const float*)d_in[7];
    const float* Wc1 = (const float*)d_in[8];
    const float* bc1 = (const float*)d_in[9];
    const float* Wc2 = (const float*)d_in[10];
    const float* bc2 = (const float*)d_in[11];
    float* out = (float*)d_out;
    float* ws  = (float*)d_ws;

    if (ws_size < (size_t)WS_FLOATS * sizeof(float)) return;  // proven available r12

    int*          slot2  = (int*)(ws + W_S2);
    int*          cnt    = (int*)(ws + W_CNT);
    float*        dinv   = ws + W_DINV;
    float4*       xd4    = (float4*)(ws + W_XD4);
    float4*       a4     = (float4*)(ws + W_A4);
    unsigned int* g1h    = (unsigned int*)(ws + W_G1H);
    int*          ovf    = (int*)(ws + W_OVF);

    hipMemsetAsync(cnt, 0, (size_t)NNODES * sizeof(int), stream);
    hipMemsetAsync(ovf, 0, sizeof(int), stream);

    k_fillbkt<<<FBLKS * NPART, 256, 0, stream>>>(ei, cnt, slot2, ovf);
    k_prep   <<<(NNODES + 255) / 256, 256, 0, stream>>>(cnt, x, dinv, xd4);
    k_a      <<<(NNODES + 255) / 256, 256, 0, stream>>>(cnt, slot2, xd4, a4);
    k_ovfA   <<<1, 256, 0, stream>>>(ovf, xd4, dinv, (float*)a4);
    k_g1     <<<(NNODES * 32) / 256, 256, 0, stream>>>(a4, W1, b1, g1h);
    k_fusedA <<<NGRAPH, 256, 0, stream>>>(cnt, slot2, ovf, g1h, dinv, mv,
                                          W2, b2, Wc1, bc1, Wc2, bc2, out);
}